// Round 1
// baseline (1416.333 us; speedup 1.0000x reference)
//
#include <hip/hip_runtime.h>
#include <stdint.h>

// LIIF fused inference for MI355X (gfx950).
// B=4, C=64, H=W=128, Q=30000, HID=256, IN_DIM=580.
//
// Pipeline:
//   prep_weights: w1 (576 rows, permuted k'=(kh*3+kw)*64+c) -> bf16 [o][k'] ; w2..w4 -> bf16 [o][k]
//   conv1:        inp -> feat bf16, CHANNEL-LAST layout [b][y][x][c]
//   layer1:       h1_pre[b][pixel][o] = sum_k featu[k]*w1[k][o] + b1[o]   (bf16 MFMA GEMM, no relu)
//   mlp_fused:    per 16 queries x 4 branches: gather h1_pre row, add rel-terms, relu,
//                 3x (256x256 bf16 MFMA GEMM + bias + relu), head w5, local-ensemble.
//
// ws layout (42,631,168 bytes needed):
//   feat   bf16  [0,        8388608)
//   h1_pre bf16  [8388608,  41943040)
//   w1pt   bf16  [41943040, 42237952)   [256][576]
//   w2t    bf16  [42237952, 42369024)   [256][256]
//   w3t    bf16  [42369024, 42500096)
//   w4t    bf16  [42500096, 42631168)

typedef unsigned short u16;
typedef __attribute__((ext_vector_type(8))) short   short8;
typedef __attribute__((ext_vector_type(8))) __bf16  bf16x8;
typedef __attribute__((ext_vector_type(4))) float   f32x4;

__device__ __forceinline__ float bf2f(u16 u) {
  union { uint32_t i; float f; } v; v.i = ((uint32_t)u) << 16; return v.f;
}
__device__ __forceinline__ u16 f2bf(float f) {
  union { float f; uint32_t i; } v; v.f = f;
  return (u16)((v.i + 0x7FFFu + ((v.i >> 16) & 1u)) >> 16);  // RNE; inputs finite
}

// ---------------------------------------------------------------- weights prep
__global__ void prep_weights(const float* __restrict__ w1, const float* __restrict__ w2,
                             const float* __restrict__ w3, const float* __restrict__ w4,
                             u16* __restrict__ w1pt, u16* __restrict__ w2t,
                             u16* __restrict__ w3t, u16* __restrict__ w4t) {
  int tid = blockIdx.x * 256 + threadIdx.x;
  const int N1 = 256 * 576;
  if (tid < N1) {
    int o = tid / 576, kk = tid - o * 576;
    int t = kk >> 6, c = kk & 63;               // k' = t*64 + c  <->  w1 row c*9+t
    w1pt[tid] = f2bf(w1[(c * 9 + t) * 256 + o]);
  } else {
    int u = tid - N1;
    if (u < 3 * 65536) {
      int layer = u >> 16, r = u & 65535;
      int o = r >> 8, k = r & 255;
      const float* src = (layer == 0) ? w2 : (layer == 1) ? w3 : w4;
      u16* dst = (layer == 0) ? w2t : (layer == 1) ? w3t : w4t;
      dst[o * 256 + k] = f2bf(src[k * 256 + o]);
    }
  }
}

// ---------------------------------------------------------------- conv 3x3, 1->64, channel-last out
__global__ void conv1_kernel(const float* __restrict__ inp, const float* __restrict__ cw,
                             const float* __restrict__ cb, u16* __restrict__ feat) {
  int tid = blockIdx.x * 256 + threadIdx.x;     // ((b*128+y)*128+x)*64 + c
  int c = tid & 63;
  int x = (tid >> 6) & 127;
  int y = (tid >> 13) & 127;
  int b = tid >> 20;
  const float* ip = inp + b * 16384;
  float s = cb[c];
  #pragma unroll
  for (int kh = 0; kh < 3; ++kh) {
    int iy = y + kh - 1;
    if (iy < 0 || iy > 127) continue;
    #pragma unroll
    for (int kw = 0; kw < 3; ++kw) {
      int ix = x + kw - 1;
      if (ix < 0 || ix > 127) continue;
      s += ip[iy * 128 + ix] * cw[c * 9 + kh * 3 + kw];
    }
  }
  feat[tid] = f2bf(s);
}

// ---------------------------------------------------------------- layer 1 as 3x3 conv-GEMM
// block: 256 thr (4 waves), M=64 pixels (b,y,x0..x0+63), N=256, K=576 in 18 tiles of 32.
__global__ __launch_bounds__(256) void layer1_kernel(const u16* __restrict__ feat,
                                                     const u16* __restrict__ w1pt,
                                                     const float* __restrict__ b1,
                                                     u16* __restrict__ h1pre) {
  __shared__ short Al[64 * 40];    // A tile [px][k] rows padded 32->40 (bank spread)
  __shared__ short Wl[256 * 40];   // W tile [n][k] rows padded 32->40

  int tid = threadIdx.x;
  int lane = tid & 63, wave = tid >> 6;
  int bid = blockIdx.x;
  int b = bid >> 8, rem = bid & 255;
  int y = rem >> 1, x0 = (rem & 1) << 6;

  f32x4 acc[4][4];
  #pragma unroll
  for (int i = 0; i < 4; ++i)
    #pragma unroll
    for (int j = 0; j < 4; ++j) acc[i][j] = (f32x4){0.f, 0.f, 0.f, 0.f};

  int apx = tid >> 2, acq = tid & 3;   // A-staging role: pixel row, 8-channel quad

  for (int kt = 0; kt < 18; ++kt) {
    __syncthreads();
    { // stage A: K-tile kt covers tap t=kt>>1, channels cbase..cbase+31
      int t = kt >> 1, cbase = (kt & 1) << 5;
      int dh = t / 3 - 1, dw = t % 3 - 1;
      int yy = y + dh;
      int xx = x0 + apx + dw;
      short8 v = {0, 0, 0, 0, 0, 0, 0, 0};
      if (yy >= 0 && yy < 128 && xx >= 0 && xx < 128)
        v = *(const short8*)(feat + (((b * 128 + yy) * 128 + xx) * 64 + cbase + acq * 8));
      *(short8*)(Al + apx * 40 + acq * 8) = v;
    }
    { // stage W: 256 rows x 64B, linear 16B chunks (j==4 is pad, skipped)
      #pragma unroll
      for (int it = 0; it < 5; ++it) {
        int ch = it * 256 + tid;
        int o = ch / 5, j = ch - o * 5;
        if (j < 4) {
          short8 v = *(const short8*)(w1pt + (o * 576 + kt * 32 + j * 8));
          *(short8*)(Wl + o * 40 + j * 8) = v;
        }
      }
    }
    __syncthreads();
    int g = lane >> 4, l15 = lane & 15;
    bf16x8 a[4];
    #pragma unroll
    for (int mf = 0; mf < 4; ++mf)
      a[mf] = *(const bf16x8*)(Al + (mf * 16 + l15) * 40 + g * 8);
    int wc0 = wave * 64;
    #pragma unroll
    for (int nf = 0; nf < 4; ++nf) {
      bf16x8 bfr = *(const bf16x8*)(Wl + (wc0 + nf * 16 + l15) * 40 + g * 8);
      #pragma unroll
      for (int mf = 0; mf < 4; ++mf)
        acc[mf][nf] = __builtin_amdgcn_mfma_f32_16x16x32_bf16(a[mf], bfr, acc[mf][nf], 0, 0, 0);
    }
  }

  // epilogue: + b1, store bf16 (NO relu; rel-terms added per query later)
  int g = lane >> 4, l15 = lane & 15;
  int wc0 = wave * 64;
  #pragma unroll
  for (int nf = 0; nf < 4; ++nf) {
    int col = wc0 + nf * 16 + l15;
    float bias = b1[col];
    #pragma unroll
    for (int mf = 0; mf < 4; ++mf)
      #pragma unroll
      for (int i = 0; i < 4; ++i) {
        int px = mf * 16 + 4 * g + i;
        int pixel = y * 128 + x0 + px;
        h1pre[(((b << 14) + pixel) << 8) + col] = f2bf(acc[mf][nf][i] + bias);
      }
  }
}

// ---------------------------------------------------------------- fused per-query MLP
// block: 256 thr (4 waves), 16 queries x 4 branches = 64 rows; waves split N (64 cols each).
__global__ __launch_bounds__(256) void mlp_kernel(
    const float* __restrict__ coord, const float* __restrict__ cell,
    const u16* __restrict__ h1pre,
    const u16* __restrict__ w2t, const u16* __restrict__ w3t, const u16* __restrict__ w4t,
    const float* __restrict__ w1, const float* __restrict__ b2, const float* __restrict__ b3,
    const float* __restrict__ b4, const float* __restrict__ w5, const float* __restrict__ b5,
    float* __restrict__ out) {
  __shared__ short Xl[64 * 264];   // activations [row][k], rows padded 256->264
  __shared__ short Wl[256 * 40];   // W K-tile [n][k], rows padded 32->40
  __shared__ float relv[64][4];    // rel0, rel1, rel_cell0, rel_cell1
  __shared__ float area_l[64];
  __shared__ int   idx_l[64];
  __shared__ float predp[4][64];   // per-wave partial head sums

  int tid = threadIdx.x;
  int lane = tid & 63, wave = tid >> 6;
  int bid = blockIdx.x;
  int b = bid / 1875;
  int q0 = (bid - b * 1875) * 16;

  // ---- phase A: per-row (query,branch) geometry
  if (tid < 64) {
    int t = tid >> 2, br = tid & 3;            // branch order matches ref: vx outer, vy inner
    int q = q0 + t;
    float c0 = coord[(b * 30000 + q) * 2 + 0];
    float c1 = coord[(b * 30000 + q) * 2 + 1];
    float ce0 = cell[(b * 30000 + q) * 2 + 0];
    float ce1 = cell[(b * 30000 + q) * 2 + 1];
    float vx = (br & 2) ? 1.0f : -1.0f;
    float vy = (br & 1) ? 1.0f : -1.0f;
    float s0 = c0 + vx * (1.0f / 128.0f) + 1e-6f;
    float s1 = c1 + vy * (1.0f / 128.0f) + 1e-6f;
    s0 = fminf(fmaxf(s0, -1.0f + 1e-6f), 1.0f - 1e-6f);
    s1 = fminf(fmaxf(s1, -1.0f + 1e-6f), 1.0f - 1e-6f);
    float fi = rintf((s0 + 1.0f) * 64.0f - 0.5f);   // (c+1)*H/2-0.5, half-to-even
    float fj = rintf((s1 + 1.0f) * 64.0f - 0.5f);
    fi = fminf(fmaxf(fi, 0.0f), 127.0f);
    fj = fminf(fmaxf(fj, 0.0f), 127.0f);
    float qy = -1.0f + (2.0f * fi + 1.0f) / 128.0f;
    float qx = -1.0f + (2.0f * fj + 1.0f) / 128.0f;
    float rel0 = (c0 - qy) * 128.0f;
    float rel1 = (c1 - qx) * 128.0f;
    idx_l[tid] = (int)fi * 128 + (int)fj;
    relv[tid][0] = rel0;
    relv[tid][1] = rel1;
    relv[tid][2] = ce0 * 128.0f;
    relv[tid][3] = ce1 * 128.0f;
    area_l[tid] = fabsf(rel0 * rel1) + 1e-9f;
  }
  __syncthreads();

  // ---- phase B: gather h1_pre rows, add rel-terms, relu -> Xl (bf16)
  {
    const float* wr = w1 + 576 * 256;   // rel rows of w1 (fp32)
    #pragma unroll
    for (int it = 0; it < 8; ++it) {
      int ch = it * 256 + tid;          // 2048 chunks: 64 rows x 32 x 16B
      int row = ch >> 5, c16 = ch & 31;
      int idx = idx_l[row];
      short8 v = *(const short8*)(h1pre + (((b << 14) + idx) << 8) + c16 * 8);
      float r0 = relv[row][0], r1 = relv[row][1], r2 = relv[row][2], r3 = relv[row][3];
      short8 xo;
      #pragma unroll
      for (int e = 0; e < 8; ++e) {
        int col = c16 * 8 + e;
        float val = bf2f((u16)v[e]) + r0 * wr[col] + r1 * wr[256 + col] +
                    r2 * wr[512 + col] + r3 * wr[768 + col];
        xo[e] = (short)f2bf(fmaxf(val, 0.0f));
      }
      *(short8*)(Xl + row * 264 + c16 * 8) = xo;
    }
  }

  int g = lane >> 4, l15 = lane & 15;
  int wc0 = wave * 64;
  const u16* Wgs[3] = {w2t, w3t, w4t};
  const float* Bgs[3] = {b2, b3, b4};
  f32x4 acc[4][4];

  #pragma unroll
  for (int layer = 0; layer < 3; ++layer) {
    const u16* Wg = Wgs[layer];
    #pragma unroll
    for (int mf = 0; mf < 4; ++mf)
      #pragma unroll
      for (int nf = 0; nf < 4; ++nf) acc[mf][nf] = (f32x4){0.f, 0.f, 0.f, 0.f};

    for (int ks = 0; ks < 8; ++ks) {
      __syncthreads();                 // prev tile fully consumed
      #pragma unroll
      for (int it = 0; it < 5; ++it) { // stage W K-tile
        int ch = it * 256 + tid;
        int o = ch / 5, j = ch - o * 5;
        if (j < 4) {
          short8 v = *(const short8*)(Wg + (o * 256 + ks * 32 + j * 8));
          *(short8*)(Wl + o * 40 + j * 8) = v;
        }
      }
      __syncthreads();
      bf16x8 a[4];
      #pragma unroll
      for (int mf = 0; mf < 4; ++mf)
        a[mf] = *(const bf16x8*)(Xl + (mf * 16 + l15) * 264 + ks * 32 + g * 8);
      #pragma unroll
      for (int nf = 0; nf < 4; ++nf) {
        bf16x8 bfr = *(const bf16x8*)(Wl + (wc0 + nf * 16 + l15) * 40 + g * 8);
        #pragma unroll
        for (int mf = 0; mf < 4; ++mf)
          acc[mf][nf] = __builtin_amdgcn_mfma_f32_16x16x32_bf16(a[mf], bfr, acc[mf][nf], 0, 0, 0);
      }
    }

    const float* bias = Bgs[layer];
    if (layer < 2) {
      __syncthreads();                 // all waves done READING Xl before overwrite
      #pragma unroll
      for (int nf = 0; nf < 4; ++nf) {
        int col = wc0 + nf * 16 + l15;
        float bv = bias[col];
        #pragma unroll
        for (int mf = 0; mf < 4; ++mf)
          #pragma unroll
          for (int i = 0; i < 4; ++i) {
            float v = fmaxf(acc[mf][nf][i] + bv, 0.0f);
            Xl[(mf * 16 + 4 * g + i) * 264 + col] = (short)f2bf(v);
          }
      }
    } else {
      // final hidden layer: relu(acc+b4) dot w5, reduce across the 16-lane col group
      float s[4][4];
      #pragma unroll
      for (int mf = 0; mf < 4; ++mf)
        #pragma unroll
        for (int i = 0; i < 4; ++i) s[mf][i] = 0.0f;
      #pragma unroll
      for (int nf = 0; nf < 4; ++nf) {
        int col = wc0 + nf * 16 + l15;
        float bv = bias[col];
        float wv = w5[col];
        #pragma unroll
        for (int mf = 0; mf < 4; ++mf)
          #pragma unroll
          for (int i = 0; i < 4; ++i)
            s[mf][i] += fmaxf(acc[mf][nf][i] + bv, 0.0f) * wv;
      }
      #pragma unroll
      for (int d = 1; d < 16; d <<= 1)
        #pragma unroll
        for (int mf = 0; mf < 4; ++mf)
          #pragma unroll
          for (int i = 0; i < 4; ++i)
            s[mf][i] += __shfl_xor(s[mf][i], d, 64);
      if (l15 == 0) {
        #pragma unroll
        for (int mf = 0; mf < 4; ++mf)
          #pragma unroll
          for (int i = 0; i < 4; ++i)
            predp[wave][mf * 16 + 4 * g + i] = s[mf][i];
      }
    }
  }
  __syncthreads();

  // ---- local ensemble (areas diagonally swapped)
  if (tid < 16) {
    int q = q0 + tid;
    float pr[4], ar[4];
    #pragma unroll
    for (int br = 0; br < 4; ++br) {
      int r = tid * 4 + br;
      pr[br] = predp[0][r] + predp[1][r] + predp[2][r] + predp[3][r] + b5[0];
      ar[br] = area_l[r];
    }
    float tot = ar[0] + ar[1] + ar[2] + ar[3];
    float ret = 0.0f;
    #pragma unroll
    for (int br = 0; br < 4; ++br) ret += pr[br] * (ar[3 - br] / tot);
    out[b * 30000 + q] = ret;
  }
}

// ---------------------------------------------------------------- launch
extern "C" void kernel_launch(void* const* d_in, const int* in_sizes, int n_in,
                              void* d_out, int out_size, void* d_ws, size_t ws_size,
                              hipStream_t stream) {
  const float* inp    = (const float*)d_in[0];
  const float* coord  = (const float*)d_in[1];
  const float* cell   = (const float*)d_in[2];
  const float* conv_w = (const float*)d_in[3];
  const float* conv_b = (const float*)d_in[4];
  const float* w1 = (const float*)d_in[5];
  const float* b1 = (const float*)d_in[6];
  const float* w2 = (const float*)d_in[7];
  const float* b2 = (const float*)d_in[8];
  const float* w3 = (const float*)d_in[9];
  const float* b3 = (const float*)d_in[10];
  const float* w4 = (const float*)d_in[11];
  const float* b4 = (const float*)d_in[12];
  const float* w5 = (const float*)d_in[13];
  const float* b5 = (const float*)d_in[14];
  float* out = (float*)d_out;

  char* ws = (char*)d_ws;
  u16* feat  = (u16*)(ws);
  u16* h1pre = (u16*)(ws + 8388608);
  u16* w1pt  = (u16*)(ws + 41943040);
  u16* w2t   = (u16*)(ws + 42237952);
  u16* w3t   = (u16*)(ws + 42369024);
  u16* w4t   = (u16*)(ws + 42500096);

  hipLaunchKernelGGL(prep_weights, dim3(1344), dim3(256), 0, stream,
                     w1, w2, w3, w4, w1pt, w2t, w3t, w4t);
  hipLaunchKernelGGL(conv1_kernel, dim3(16384), dim3(256), 0, stream,
                     inp, conv_w, conv_b, feat);
  hipLaunchKernelGGL(layer1_kernel, dim3(1024), dim3(256), 0, stream,
                     feat, w1pt, b1, h1pre);
  hipLaunchKernelGGL(mlp_kernel, dim3(7500), dim3(256), 0, stream,
                     coord, cell, h1pre, w2t, w3t, w4t, w1, b2, b3, b4, w5, b5, out);
}

// Round 2
// 1098.804 us; speedup vs baseline: 1.2890x; 1.2890x over previous
//
#include <hip/hip_runtime.h>
#include <stdint.h>

// LIIF fused inference for MI355X (gfx950).
// B=4, C=64, H=W=128, Q=30000, HID=256, IN_DIM=580.
//
// Pipeline:
//   prep_weights: w1 (576 rows, permuted k'=(kh*3+kw)*64+c) -> bf16 [o][k'] ; w2..w4 -> bf16 [o][k]
//   conv1:        inp -> feat bf16, CHANNEL-LAST layout [b][y][x][c]
//   layer1:       h1_pre[b][pixel][o] = sum_k featu[k]*w1[k][o] + b1[o]   (bf16 MFMA GEMM, no relu)
//   mlp_fused v2: 512 thr / 8 waves, 128 rows (32 queries x 4 branches) per block.
//                 B-fragments load DIRECTLY from global (L2-resident weights, no LDS staging,
//                 no k-loop barriers), prefetched one k-step ahead. X stays in LDS (padded rows).
//
// ws layout (42,631,168 bytes):
//   feat   bf16  [0,        8388608)
//   h1_pre bf16  [8388608,  41943040)
//   w1pt   bf16  [41943040, 42237952)   [256][576]
//   w2t    bf16  [42237952, 42369024)   [256][256]  (w2t[o][k] = w2[k][o])
//   w3t    bf16  [42369024, 42500096)
//   w4t    bf16  [42500096, 42631168)

typedef unsigned short u16;
typedef __attribute__((ext_vector_type(8))) short   short8;
typedef __attribute__((ext_vector_type(8))) __bf16  bf16x8;
typedef __attribute__((ext_vector_type(4))) float   f32x4;

__device__ __forceinline__ float bf2f(u16 u) {
  union { uint32_t i; float f; } v; v.i = ((uint32_t)u) << 16; return v.f;
}
__device__ __forceinline__ u16 f2bf(float f) {
  union { float f; uint32_t i; } v; v.f = f;
  return (u16)((v.i + 0x7FFFu + ((v.i >> 16) & 1u)) >> 16);  // RNE; inputs finite
}

// ---------------------------------------------------------------- weights prep
__global__ void prep_weights(const float* __restrict__ w1, const float* __restrict__ w2,
                             const float* __restrict__ w3, const float* __restrict__ w4,
                             u16* __restrict__ w1pt, u16* __restrict__ w2t,
                             u16* __restrict__ w3t, u16* __restrict__ w4t) {
  int tid = blockIdx.x * 256 + threadIdx.x;
  const int N1 = 256 * 576;
  if (tid < N1) {
    int o = tid / 576, kk = tid - o * 576;
    int t = kk >> 6, c = kk & 63;               // k' = t*64 + c  <->  w1 row c*9+t
    w1pt[tid] = f2bf(w1[(c * 9 + t) * 256 + o]);
  } else {
    int u = tid - N1;
    if (u < 3 * 65536) {
      int layer = u >> 16, r = u & 65535;
      int o = r >> 8, k = r & 255;
      const float* src = (layer == 0) ? w2 : (layer == 1) ? w3 : w4;
      u16* dst = (layer == 0) ? w2t : (layer == 1) ? w3t : w4t;
      dst[o * 256 + k] = f2bf(src[k * 256 + o]);
    }
  }
}

// ---------------------------------------------------------------- conv 3x3, 1->64, channel-last out
__global__ void conv1_kernel(const float* __restrict__ inp, const float* __restrict__ cw,
                             const float* __restrict__ cb, u16* __restrict__ feat) {
  int tid = blockIdx.x * 256 + threadIdx.x;     // ((b*128+y)*128+x)*64 + c
  int c = tid & 63;
  int x = (tid >> 6) & 127;
  int y = (tid >> 13) & 127;
  int b = tid >> 20;
  const float* ip = inp + b * 16384;
  float s = cb[c];
  #pragma unroll
  for (int kh = 0; kh < 3; ++kh) {
    int iy = y + kh - 1;
    if (iy < 0 || iy > 127) continue;
    #pragma unroll
    for (int kw = 0; kw < 3; ++kw) {
      int ix = x + kw - 1;
      if (ix < 0 || ix > 127) continue;
      s += ip[iy * 128 + ix] * cw[c * 9 + kh * 3 + kw];
    }
  }
  feat[tid] = f2bf(s);
}

// ---------------------------------------------------------------- layer 1 as 3x3 conv-GEMM
// block: 256 thr (4 waves), M=64 pixels (b,y,x0..x0+63), N=256, K=576 in 18 tiles of 32.
__global__ __launch_bounds__(256) void layer1_kernel(const u16* __restrict__ feat,
                                                     const u16* __restrict__ w1pt,
                                                     const float* __restrict__ b1,
                                                     u16* __restrict__ h1pre) {
  __shared__ short Al[64 * 40];    // A tile [px][k] rows padded 32->40 (bank spread)
  __shared__ short Wl[256 * 40];   // W tile [n][k] rows padded 32->40

  int tid = threadIdx.x;
  int lane = tid & 63, wave = tid >> 6;
  int bid = blockIdx.x;
  int b = bid >> 8, rem = bid & 255;
  int y = rem >> 1, x0 = (rem & 1) << 6;

  f32x4 acc[4][4];
  #pragma unroll
  for (int i = 0; i < 4; ++i)
    #pragma unroll
    for (int j = 0; j < 4; ++j) acc[i][j] = (f32x4){0.f, 0.f, 0.f, 0.f};

  int apx = tid >> 2, acq = tid & 3;   // A-staging role: pixel row, 8-channel quad

  for (int kt = 0; kt < 18; ++kt) {
    __syncthreads();
    { // stage A: K-tile kt covers tap t=kt>>1, channels cbase..cbase+31
      int t = kt >> 1, cbase = (kt & 1) << 5;
      int dh = t / 3 - 1, dw = t % 3 - 1;
      int yy = y + dh;
      int xx = x0 + apx + dw;
      short8 v = {0, 0, 0, 0, 0, 0, 0, 0};
      if (yy >= 0 && yy < 128 && xx >= 0 && xx < 128)
        v = *(const short8*)(feat + (((b * 128 + yy) * 128 + xx) * 64 + cbase + acq * 8));
      *(short8*)(Al + apx * 40 + acq * 8) = v;
    }
    { // stage W: 256 rows x 64B, linear 16B chunks (j==4 is pad, skipped)
      #pragma unroll
      for (int it = 0; it < 5; ++it) {
        int ch = it * 256 + tid;
        int o = ch / 5, j = ch - o * 5;
        if (j < 4) {
          short8 v = *(const short8*)(w1pt + (o * 576 + kt * 32 + j * 8));
          *(short8*)(Wl + o * 40 + j * 8) = v;
        }
      }
    }
    __syncthreads();
    int g = lane >> 4, l15 = lane & 15;
    bf16x8 a[4];
    #pragma unroll
    for (int mf = 0; mf < 4; ++mf)
      a[mf] = *(const bf16x8*)(Al + (mf * 16 + l15) * 40 + g * 8);
    int wc0 = wave * 64;
    #pragma unroll
    for (int nf = 0; nf < 4; ++nf) {
      bf16x8 bfr = *(const bf16x8*)(Wl + (wc0 + nf * 16 + l15) * 40 + g * 8);
      #pragma unroll
      for (int mf = 0; mf < 4; ++mf)
        acc[mf][nf] = __builtin_amdgcn_mfma_f32_16x16x32_bf16(a[mf], bfr, acc[mf][nf], 0, 0, 0);
    }
  }

  // epilogue: + b1, store bf16 (NO relu; rel-terms added per query later)
  int g = lane >> 4, l15 = lane & 15;
  int wc0 = wave * 64;
  #pragma unroll
  for (int nf = 0; nf < 4; ++nf) {
    int col = wc0 + nf * 16 + l15;
    float bias = b1[col];
    #pragma unroll
    for (int mf = 0; mf < 4; ++mf)
      #pragma unroll
      for (int i = 0; i < 4; ++i) {
        int px = mf * 16 + 4 * g + i;
        int pixel = y * 128 + x0 + px;
        h1pre[(((b << 14) + pixel) << 8) + col] = f2bf(acc[mf][nf][i] + bias);
      }
  }
}

// ---------------------------------------------------------------- fused per-query MLP v2
// block: 512 thr (8 waves), 32 queries x 4 branches = 128 rows.
// wave grid 2x4: row-group rr0 = (wave>>2)*64, col-group wc0 = (wave&3)*64.
// Weights: B-fragments loaded DIRECTLY from global (L2-resident), prefetch 1 k-step.
__global__ __launch_bounds__(512) void mlp_kernel(
    const float* __restrict__ coord, const float* __restrict__ cell,
    const u16* __restrict__ h1pre,
    const u16* __restrict__ w2t, const u16* __restrict__ w3t, const u16* __restrict__ w4t,
    const float* __restrict__ w1, const float* __restrict__ b2, const float* __restrict__ b3,
    const float* __restrict__ b4, const float* __restrict__ w5, const float* __restrict__ b5,
    float* __restrict__ out) {
  __shared__ short Xl[128 * 264];  // activations [row][k], rows padded 256->264 (528 B)
  __shared__ float relv[128][4];   // rel0, rel1, rel_cell0, rel_cell1
  __shared__ float area_l[128];
  __shared__ int   idx_l[128];     // (b<<14) + pixel
  __shared__ float predp[4][128];  // per-colwave partial head sums

  int tid = threadIdx.x;
  int lane = tid & 63, wave = tid >> 6;
  int g = lane >> 4, l15 = lane & 15;
  int rr0 = (wave >> 2) * 64;      // wave's row group
  int wc0 = (wave & 3) * 64;       // wave's col group
  int bid = blockIdx.x;            // 3750 blocks x 32 queries

  // ---- phase A: per-row (query,branch) geometry
  if (tid < 128) {
    int t = tid >> 2, br = tid & 3;            // branch order: vx outer, vy inner
    int gq = bid * 32 + t;                     // global query index, coord/cell/out flat index
    int b = gq / 30000;
    float c0 = coord[gq * 2 + 0];
    float c1 = coord[gq * 2 + 1];
    float ce0 = cell[gq * 2 + 0];
    float ce1 = cell[gq * 2 + 1];
    float vx = (br & 2) ? 1.0f : -1.0f;
    float vy = (br & 1) ? 1.0f : -1.0f;
    float s0 = c0 + vx * (1.0f / 128.0f) + 1e-6f;
    float s1 = c1 + vy * (1.0f / 128.0f) + 1e-6f;
    s0 = fminf(fmaxf(s0, -1.0f + 1e-6f), 1.0f - 1e-6f);
    s1 = fminf(fmaxf(s1, -1.0f + 1e-6f), 1.0f - 1e-6f);
    float fi = rintf((s0 + 1.0f) * 64.0f - 0.5f);   // (c+1)*H/2-0.5, half-to-even
    float fj = rintf((s1 + 1.0f) * 64.0f - 0.5f);
    fi = fminf(fmaxf(fi, 0.0f), 127.0f);
    fj = fminf(fmaxf(fj, 0.0f), 127.0f);
    float qy = -1.0f + (2.0f * fi + 1.0f) / 128.0f;
    float qx = -1.0f + (2.0f * fj + 1.0f) / 128.0f;
    float rel0 = (c0 - qy) * 128.0f;
    float rel1 = (c1 - qx) * 128.0f;
    idx_l[tid] = (b << 14) + (int)fi * 128 + (int)fj;
    relv[tid][0] = rel0;
    relv[tid][1] = rel1;
    relv[tid][2] = ce0 * 128.0f;
    relv[tid][3] = ce1 * 128.0f;
    area_l[tid] = fabsf(rel0 * rel1) + 1e-9f;
  }
  __syncthreads();

  // ---- phase B: gather h1_pre rows, add rel-terms, relu -> Xl (bf16)
  {
    const float* wr = w1 + 576 * 256;   // rel rows of w1 (fp32), [4][256]
    short8 v[8];
    #pragma unroll
    for (int it = 0; it < 8; ++it) {    // issue all 8 loads first (latency overlap)
      int ch = it * 512 + tid;          // 4096 chunks: 128 rows x 32 x 16B
      int row = ch >> 5, c16 = ch & 31;
      v[it] = *(const short8*)(h1pre + ((size_t)idx_l[row] << 8) + c16 * 8);
    }
    #pragma unroll
    for (int it = 0; it < 8; ++it) {
      int ch = it * 512 + tid;
      int row = ch >> 5, c16 = ch & 31;
      float r0 = relv[row][0], r1 = relv[row][1], r2 = relv[row][2], r3 = relv[row][3];
      short8 xo;
      #pragma unroll
      for (int e = 0; e < 8; ++e) {
        int col = c16 * 8 + e;
        float val = bf2f((u16)v[it][e]) + r0 * wr[col] + r1 * wr[256 + col] +
                    r2 * wr[512 + col] + r3 * wr[768 + col];
        xo[e] = (short)f2bf(fmaxf(val, 0.0f));
      }
      *(short8*)(Xl + row * 264 + c16 * 8) = xo;
    }
  }
  __syncthreads();

  const u16* Wgs[3] = {w2t, w3t, w4t};
  const float* Bgs[3] = {b2, b3, b4};
  f32x4 acc[4][4];

  #pragma unroll
  for (int layer = 0; layer < 3; ++layer) {
    const u16* Wg = Wgs[layer];
    #pragma unroll
    for (int mf = 0; mf < 4; ++mf)
      #pragma unroll
      for (int nf = 0; nf < 4; ++nf) acc[mf][nf] = (f32x4){0.f, 0.f, 0.f, 0.f};

    // k-loop: NO barriers. B-frags straight from global (L2), prefetched 1 step.
    bf16x8 bcur[4];
    #pragma unroll
    for (int nf = 0; nf < 4; ++nf)
      bcur[nf] = *(const bf16x8*)(Wg + (wc0 + nf * 16 + l15) * 256 + g * 8);
    #pragma unroll
    for (int ks = 0; ks < 8; ++ks) {
      bf16x8 bnxt[4];
      if (ks < 7) {
        #pragma unroll
        for (int nf = 0; nf < 4; ++nf)
          bnxt[nf] = *(const bf16x8*)(Wg + (wc0 + nf * 16 + l15) * 256 + (ks + 1) * 32 + g * 8);
      }
      bf16x8 a[4];
      #pragma unroll
      for (int mf = 0; mf < 4; ++mf)
        a[mf] = *(const bf16x8*)(Xl + (rr0 + mf * 16 + l15) * 264 + ks * 32 + g * 8);
      #pragma unroll
      for (int nf = 0; nf < 4; ++nf)
        #pragma unroll
        for (int mf = 0; mf < 4; ++mf)
          acc[mf][nf] = __builtin_amdgcn_mfma_f32_16x16x32_bf16(a[mf], bcur[nf], acc[mf][nf], 0, 0, 0);
      if (ks < 7) {
        #pragma unroll
        for (int nf = 0; nf < 4; ++nf) bcur[nf] = bnxt[nf];
      }
    }

    const float* bias = Bgs[layer];
    __syncthreads();                 // all waves done READING Xl before overwrite
    if (layer < 2) {
      #pragma unroll
      for (int nf = 0; nf < 4; ++nf) {
        int col = wc0 + nf * 16 + l15;
        float bv = bias[col];
        #pragma unroll
        for (int mf = 0; mf < 4; ++mf)
          #pragma unroll
          for (int i = 0; i < 4; ++i) {
            float v = fmaxf(acc[mf][nf][i] + bv, 0.0f);
            Xl[(rr0 + mf * 16 + 4 * g + i) * 264 + col] = (short)f2bf(v);
          }
      }
      __syncthreads();
    } else {
      // final hidden layer: relu(acc+b4) dot w5, reduce across the 16-lane col group
      float s[4][4];
      #pragma unroll
      for (int mf = 0; mf < 4; ++mf)
        #pragma unroll
        for (int i = 0; i < 4; ++i) s[mf][i] = 0.0f;
      #pragma unroll
      for (int nf = 0; nf < 4; ++nf) {
        int col = wc0 + nf * 16 + l15;
        float bv = bias[col];
        float wv = w5[col];
        #pragma unroll
        for (int mf = 0; mf < 4; ++mf)
          #pragma unroll
          for (int i = 0; i < 4; ++i)
            s[mf][i] += fmaxf(acc[mf][nf][i] + bv, 0.0f) * wv;
      }
      #pragma unroll
      for (int d = 1; d < 16; d <<= 1)
        #pragma unroll
        for (int mf = 0; mf < 4; ++mf)
          #pragma unroll
          for (int i = 0; i < 4; ++i)
            s[mf][i] += __shfl_xor(s[mf][i], d, 64);
      if (l15 == 0) {
        #pragma unroll
        for (int mf = 0; mf < 4; ++mf)
          #pragma unroll
          for (int i = 0; i < 4; ++i)
            predp[wave & 3][rr0 + mf * 16 + 4 * g + i] = s[mf][i];
      }
    }
  }
  __syncthreads();

  // ---- local ensemble (areas diagonally swapped)
  if (tid < 32) {
    int gq = bid * 32 + tid;
    float pr[4], ar[4];
    #pragma unroll
    for (int br = 0; br < 4; ++br) {
      int r = tid * 4 + br;
      pr[br] = predp[0][r] + predp[1][r] + predp[2][r] + predp[3][r] + b5[0];
      ar[br] = area_l[r];
    }
    float tot = ar[0] + ar[1] + ar[2] + ar[3];
    float ret = 0.0f;
    #pragma unroll
    for (int br = 0; br < 4; ++br) ret += pr[br] * (ar[3 - br] / tot);
    out[gq] = ret;
  }
}

// ---------------------------------------------------------------- launch
extern "C" void kernel_launch(void* const* d_in, const int* in_sizes, int n_in,
                              void* d_out, int out_size, void* d_ws, size_t ws_size,
                              hipStream_t stream) {
  const float* inp    = (const float*)d_in[0];
  const float* coord  = (const float*)d_in[1];
  const float* cell   = (const float*)d_in[2];
  const float* conv_w = (const float*)d_in[3];
  const float* conv_b = (const float*)d_in[4];
  const float* w1 = (const float*)d_in[5];
  const float* b1 = (const float*)d_in[6];
  const float* w2 = (const float*)d_in[7];
  const float* b2 = (const float*)d_in[8];
  const float* w3 = (const float*)d_in[9];
  const float* b3 = (const float*)d_in[10];
  const float* w4 = (const float*)d_in[11];
  const float* b4 = (const float*)d_in[12];
  const float* w5 = (const float*)d_in[13];
  const float* b5 = (const float*)d_in[14];
  float* out = (float*)d_out;

  char* ws = (char*)d_ws;
  u16* feat  = (u16*)(ws);
  u16* h1pre = (u16*)(ws + 8388608);
  u16* w1pt  = (u16*)(ws + 41943040);
  u16* w2t   = (u16*)(ws + 42237952);
  u16* w3t   = (u16*)(ws + 42369024);
  u16* w4t   = (u16*)(ws + 42500096);

  hipLaunchKernelGGL(prep_weights, dim3(1344), dim3(256), 0, stream,
                     w1, w2, w3, w4, w1pt, w2t, w3t, w4t);
  hipLaunchKernelGGL(conv1_kernel, dim3(16384), dim3(256), 0, stream,
                     inp, conv_w, conv_b, feat);
  hipLaunchKernelGGL(layer1_kernel, dim3(1024), dim3(256), 0, stream,
                     feat, w1pt, b1, h1pre);
  hipLaunchKernelGGL(mlp_kernel, dim3(3750), dim3(512), 0, stream,
                     coord, cell, h1pre, w2t, w3t, w4t, w1, b2, b3, b4, w5, b5, out);
}